// Round 8
// baseline (775.519 us; speedup 1.0000x reference)
//
#include <hip/hip_runtime.h>

#define NCLS 80
#define NMK  32
#define NB   8400
#define MH_  160
#define MP   25600     // 160*160
#define IH   640
#define IW   640
#define KTOP 100
#define CONFT 0.4f
#define IOUT 0.7f
#define T_PRE 384        // NMS prefix handled by bit-matrix (6 tiles of 64)
#define TW   (T_PRE/64)  // 6 u64 words per row
#define NBLK 640         // 640 blocks * 256 thr; <=3 blk/CU needed, capacity 8 -> all resident

// hand-rolled grid barrier: monotone counter, release-add + acquire-spin (agent scope)
__device__ __forceinline__ void gsync(int* bar, int target){
  __syncthreads();
  if (threadIdx.x == 0){
    __threadfence();
    __hip_atomic_fetch_add(bar, 1, __ATOMIC_RELEASE, __HIP_MEMORY_SCOPE_AGENT);
    while (__hip_atomic_load(bar, __ATOMIC_ACQUIRE, __HIP_MEMORY_SCOPE_AGENT) < target)
      __builtin_amdgcn_s_sleep(16);
    __threadfence();
  }
  __syncthreads();
}

__global__ __launch_bounds__(256, 3) void k_all(
    const float* __restrict__ det, const float* __restrict__ proto,
    float* __restrict__ key, int* __restrict__ cid, int* __restrict__ rankv,
    int* __restrict__ perm, int* __restrict__ scid, float4* __restrict__ sbox,
    unsigned long long* __restrict__ supmat, int* __restrict__ nvp,
    int* __restrict__ selorig, int4* __restrict__ selbox, int* __restrict__ selcid,
    int* __restrict__ nsel, unsigned int* __restrict__ hb, float* __restrict__ out,
    int* __restrict__ bar)
{
  const int bid  = blockIdx.x;
  const int tid  = threadIdx.x;
  const int lane = tid & 63;
  const int wv   = tid >> 6;
  __shared__ __align__(16) char sbuf[18432];  // P2: rank tile | P5: lsup | P7: paint arrays
  __shared__ int keptpos[KTOP];
  __shared__ int s_misc[8];

  // ---------- P1: prep (score/argmax/key + per-wave valid partials) ----------
  if (bid < 33){
    int n = bid*256 + tid;
    bool valid = false;
    if (n < NB){
      float best = det[4*NB + n];
      int bc = 0;
      #pragma unroll 8
      for (int c = 1; c < NCLS; ++c){
        float v = det[(4+c)*NB + n];
        if (v > best){ best = v; bc = c; }   // strict > keeps FIRST max (matches jnp.argmax)
      }
      cid[n] = bc;
      valid = best >= CONFT;
      key[n] = valid ? -best : __builtin_inff();  // ascending argsort key; inf sorts last
      rankv[n] = 0;
    }
    unsigned long long bal = __ballot(valid);
    if (lane == 0) nvp[bid*4 + wv] = (int)__popcll(bal);
  }
  gsync(bar, 1*NBLK);

  // ---------- P2: O(N^2) stable rank, 33 n-blocks x 16 j-slices = 528 tasks ----------
  if (bid < 528){
    float* tk = (float*)sbuf;
    int nb = bid >> 4, js = bid & 15;
    int n = nb*256 + tid;
    float kn = (n < NB) ? key[n] : 0.f;
    int j0 = js*525, j1 = j0 + 525;        // 16*525 == 8400
    int part = 0;
    for (int t0 = j0; t0 < j1; t0 += 256){
      int j = t0 + tid;
      tk[tid] = (j < NB) ? key[j] : 0.f;
      __syncthreads();
      int lim = min(256, j1 - t0);
      for (int jj = 0; jj < lim; ++jj){
        float kj = tk[jj];
        part += ((kj < kn) || (kj == kn && (t0 + jj) < n)) ? 1 : 0;  // stable: ties by index
      }
      __syncthreads();
    }
    if (n < NB && part) atomicAdd(&rankv[n], part);
  }
  gsync(bar, 2*NBLK);

  // ---------- P3: scatter into sorted order ----------
  if (bid < 33){
    int n = bid*256 + tid;
    if (n < NB){
      int r = rankv[n];
      perm[r] = n;
      scid[r] = cid[n];
      float4 b;
      b.x = det[0*NB + n]; b.y = det[1*NB + n];
      b.z = det[2*NB + n]; b.w = det[3*NB + n];
      sbox[r] = b;
    }
  }
  gsync(bar, 3*NBLK);

  // ---------- P4: suppression bit-matrix, one wave per 64x64 tile (36 tiles) ----------
  if (bid < 9){
    int t = bid*4 + wv;
    if (t < TW*TW){
      const int ti = t / TW, tj = t % TW;
      float4 bj = sbox[tj*64 + lane];
      float aj = (bj.z - bj.x) * (bj.w - bj.y);
      float4 bi_all = sbox[ti*64 + lane];
      float ai_all  = (bi_all.z - bi_all.x) * (bi_all.w - bi_all.y);
      const int jg = tj*64 + lane;
      unsigned long long myrow = 0ull;
      #pragma unroll 4
      for (int ii = 0; ii < 64; ++ii){
        float bix = __shfl(bi_all.x, ii, 64);
        float biy = __shfl(bi_all.y, ii, 64);
        float biz = __shfl(bi_all.z, ii, 64);
        float biw = __shfl(bi_all.w, ii, 64);
        float ai  = __shfl(ai_all,  ii, 64);
        float ix1 = fmaxf(bix, bj.x), iy1 = fmaxf(biy, bj.y);
        float ix2 = fminf(biz, bj.z), iy2 = fminf(biw, bj.w);
        float inter = fmaxf(ix2 - ix1, 0.f) * fmaxf(iy2 - iy1, 0.f);
        bool sup = (jg > ti*64 + ii) && (inter / (ai + aj - inter) >= IOUT);  // exact ref fp32 expr
        unsigned long long bal = __ballot(sup);
        if (lane == ii) myrow = bal;
      }
      supmat[(size_t)(ti*64 + lane)*TW + tj] = myrow;
    }
  }
  gsync(bar, 4*NBLK);

  // ---------- P5: greedy scan (block 0 only) ----------
  if (bid == 0){
    unsigned long long* lsup = (unsigned long long*)sbuf;   // 18432 B
    {
      const float4* g4 = (const float4*)supmat;
      float4* l4 = (float4*)sbuf;
      for (int idx = tid; idx < (T_PRE*TW)/2; idx += 256) l4[idx] = g4[idx];
    }
    // nvalid = sum(nvp[0..131])
    {
      int v = (tid < 132) ? nvp[tid] : 0;
      #pragma unroll
      for (int s = 32; s > 0; s >>= 1) v += __shfl_xor(v, s, 64);
      if (lane == 0) s_misc[2 + wv] = v;
    }
    __syncthreads();
    if (tid == 0) s_misc[0] = s_misc[2] + s_misc[3] + s_misc[4] + s_misc[5];
    __syncthreads();

    if (tid < 64){
      const int nv = s_misc[0];
      // keep-word init: sorted position valid <=> pos < nvalid (finite keys sort first)
      unsigned long long keepw = 0ull;
      if (lane < TW){
        int nbits = nv - lane*64;
        if (nbits >= 64) keepw = ~0ull;
        else if (nbits > 0) keepw = (1ull << nbits) - 1ull;
      }
      int found = 0;
      const int lim = min(nv, T_PRE);
      // sequential candidate scan; static rows -> unconditional depth-2 prefetch
      unsigned long long r0 = (lane < TW) ? lsup[0*TW + lane] : 0ull;
      unsigned long long r1 = (lane < TW) ? lsup[1*TW + lane] : 0ull;
      for (int cand = 0; cand < lim; ++cand){
        unsigned long long r2 = (lane < TW && cand + 2 < T_PRE) ? lsup[(cand+2)*TW + lane] : 0ull;
        bool mine = (lane == (cand >> 6)) && ((keepw >> (cand & 63)) & 1ull);
        if (__ballot(mine)){                  // candidate still alive -> keep it
          if (lane == 0) keptpos[found] = cand;
          found++;
          if (found >= KTOP) break;           // 100th kept never needs to suppress
          keepw &= ~r0;                       // suppress its victims
        }
        r0 = r1; r1 = r2;
      }
      // exact fallback over sorted positions >= T_PRE (never taken on this data)
      if (found < KTOP && nv > T_PRE){
        float4 kbA = make_float4(0.f,0.f,0.f,0.f);
        float4 kbB = make_float4(0.f,0.f,0.f,0.f);
        if (lane < found)      kbA = sbox[keptpos[lane]];
        if (lane + 64 < found) kbB = sbox[keptpos[lane + 64]];
        for (int j = T_PRE; j < nv && found < KTOP; ++j){
          float4 bj = sbox[j];
          float ajj = (bj.z - bj.x) * (bj.w - bj.y);
          bool s = false;
          if (lane < found){
            float ka = (kbA.z - kbA.x) * (kbA.w - kbA.y);
            float ix1 = fmaxf(kbA.x, bj.x), iy1 = fmaxf(kbA.y, bj.y);
            float ix2 = fminf(kbA.z, bj.z), iy2 = fminf(kbA.w, bj.w);
            float inter = fmaxf(ix2 - ix1, 0.f) * fmaxf(iy2 - iy1, 0.f);
            s = inter / (ka + ajj - inter) >= IOUT;
          }
          if (lane + 64 < found){
            float ka = (kbB.z - kbB.x) * (kbB.w - kbB.y);
            float ix1 = fmaxf(kbB.x, bj.x), iy1 = fmaxf(kbB.y, bj.y);
            float ix2 = fminf(kbB.z, bj.z), iy2 = fminf(kbB.w, bj.w);
            float inter = fmaxf(ix2 - ix1, 0.f) * fmaxf(iy2 - iy1, 0.f);
            s = s || (inter / (ka + ajj - inter) >= IOUT);
          }
          if (!__ballot(s)){
            if (lane == 0) keptpos[found] = j;
            if (found < 64){ if (lane == found) kbA = bj; }
            else           { if (lane == found - 64) kbB = bj; }
            found++;
          }
        }
      }
      if (lane == 0) s_misc[1] = found;
    }
    __syncthreads();
    const int ns = s_misc[1];
    if (tid < ns){
      int si = keptpos[tid];
      float4 b = sbox[si];
      selorig[tid] = perm[si];
      selbox[tid]  = make_int4((int)b.x, (int)b.y, (int)b.z, (int)b.w); // trunc==floor, coords>=0
      selcid[tid]  = scid[si];
    }
    if (tid == 0) *nsel = ns;
  }
  gsync(bar, 5*NBLK);

  // ---------- P6: mask logits (32-dot) -> hard bits, 1000 tasks ----------
  {
    const int ns = *nsel;
    for (int t = bid; t < 1000; t += NBLK){
      int pb = t % 100, ks = t / 100;
      int p = pb*256 + tid;                   // 0..25599
      float pr[NMK];
      #pragma unroll
      for (int m = 0; m < NMK; ++m) pr[m] = proto[m*MP + p];
      int wbase = (pb*256 + (tid & ~63)) >> 5;
      int k0 = ks*10;
      for (int kk = 0; kk < 10; ++kk){
        int k = k0 + kk;
        if (k >= ns) break;                   // uniform
        int so = selorig[k];
        const float* cf = det + 84*NB + so;   // uniform -> scalar loads
        float acc = 0.f;
        #pragma unroll
        for (int m = 0; m < NMK; ++m) acc = fmaf(cf[(size_t)m*NB], pr[m], acc);
        unsigned long long bal = __ballot(acc > 0.f);     // hard = sigmoid>0.5 <=> logit>0
        if (lane == 0)  hb[k*800 + wbase]     = (unsigned int)bal;
        if (lane == 32) hb[k*800 + wbase + 1] = (unsigned int)(bal >> 32);
      }
    }
  }
  gsync(bar, 6*NBLK);

  // ---------- P7: paint, exactly one row per block ----------
  {
    int4*  psbx   = (int4*)sbuf;              // 1600 B
    int*   pscd   = (int*)(sbuf + 1600);      // 400 B
    short* pwcls  = (short*)(sbuf + 2000);    // 1280 B
    short* pclist = (short*)(sbuf + 3280);    // 200 B
    const int ns = *nsel;
    const int y = bid;
    if (tid < ns){ psbx[tid] = selbox[tid]; pscd[tid] = selcid[tid]; }
    __syncthreads();
    if (tid < 64){  // wave0: ballot-prefix build of row candidate list (ascending k)
      bool h0 = (tid < ns) && y >= psbx[tid].y && y < psbx[tid].w;
      unsigned long long m0 = __ballot(h0);
      if (h0) pclist[(int)__popcll(m0 & ((1ull << tid) - 1ull))] = (short)tid;
      int k1 = tid + 64;
      bool h1 = (k1 < ns) && y >= psbx[k1].y && y < psbx[k1].w;
      unsigned long long m1 = __ballot(h1);
      int base = (int)__popcll(m0);
      if (h1) pclist[base + (int)__popcll(m1 & ((1ull << tid) - 1ull))] = (short)k1;
      if (tid == 0) s_misc[0] = base + (int)__popcll(m1);
    }
    __syncthreads();
    const int m = s_misc[0];
    const int fyi = (y - 2) >> 2;                      // floor((y+0.5)/4 - 0.5)
    const int ylo = max(fyi, 0), yhi = min(fyi + 1, MH_ - 1);
    for (int x = tid; x < IW; x += 256){
      int cls = -1;
      for (int ci = m - 1; ci >= 0; --ci){             // highest k containing pixel wins
        int k = pclist[ci];
        int4 b = psbx[k];
        if (x >= b.x && x < b.z){
          int fx = (x - 2) >> 2;
          int xlo = max(fx, 0), xhi = min(fx + 1, MH_ - 1);
          bool on = false;
          for (int ry = ylo; ry <= yhi; ++ry)
            for (int rx = xlo; rx <= xhi; ++rx){
              int pp = ry*MH_ + rx;
              on = on || ((hb[k*800 + (pp >> 5)] >> (pp & 31)) & 1u);
            }
          cls = on ? pscd[k] : -1;                     // painted-zero == untouched-zero
          break;
        }
      }
      pwcls[x] = (short)cls;
    }
    __syncthreads();
    // write 640*80 floats for this row, float4-coalesced (80 % 4 == 0)
    float4* o4 = (float4*)(out + (size_t)y * (IW*NCLS));
    for (int it = 0; it < 50; ++it){
      int f4 = it*256 + tid;         // 0..12799
      int x  = f4 / 20;
      int c  = (f4 % 20) * 4;
      int wc = pwcls[x];
      float4 v;
      v.x = (wc == c    ) ? 1.f : 0.f;
      v.y = (wc == c + 1) ? 1.f : 0.f;
      v.z = (wc == c + 2) ? 1.f : 0.f;
      v.w = (wc == c + 3) ? 1.f : 0.f;
      o4[f4] = v;
    }
  }
}

extern "C" void kernel_launch(void* const* d_in, const int* in_sizes, int n_in,
                              void* d_out, int out_size, void* d_ws, size_t ws_size,
                              hipStream_t stream)
{
  const float* det   = (const float*)d_in[0];   // (1,116,8400)
  const float* proto = (const float*)d_in[1];   // (1,32,160,160)
  float* out = (float*)d_out;                   // (1,640,640,80)
  char* w = (char*)d_ws;
  float*  key     = (float*)(w + 0);            // 33600
  int*    cid     = (int*)  (w + 33600);        // 33600
  int*    rankv   = (int*)  (w + 67200);        // 33600
  int*    perm    = (int*)  (w + 100800);       // 33600
  int*    scid    = (int*)  (w + 134400);       // 33600
  float4* sbox    = (float4*)(w + 168000);      // 134400, 16B aligned
  int*    selorig = (int*)  (w + 302400);       // 400
  int4*   selbox  = (int4*) (w + 302800);       // 1600, 16B aligned
  int*    selcid  = (int*)  (w + 304400);       // 400
  int*    nsel    = (int*)  (w + 304800);       // 4
  int*    nvp     = (int*)  (w + 304832);       // 528
  int*    bar     = (int*)  (w + 305376);       // 4 (barrier counter)
  unsigned int* hb = (unsigned int*)(w + 305408);                 // 320000
  unsigned long long* supmat = (unsigned long long*)(w + 625408); // 18432

  hipMemsetAsync(bar, 0, 4, stream);
  hipLaunchKernelGGL(k_all, dim3(NBLK), dim3(256), 0, stream,
                     det, proto, key, cid, rankv, perm, scid, sbox, supmat, nvp,
                     selorig, selbox, selcid, nsel, hb, out, bar);
}

// Round 11
// 378.462 us; speedup vs baseline: 2.0491x; 2.0491x over previous
//
#include <hip/hip_runtime.h>

#define NCLS 80
#define NMK  32
#define NB   8400
#define MH_  160
#define MP   25600     // 160*160
#define IH   640
#define IW   640
#define KTOP 100
#define CONFT 0.4f
#define IOUT 0.7f
#define T_PRE 384        // NMS prefix handled by bit-matrix (6 tiles of 64)
#define TW   (T_PRE/64)  // 6 u64 words per row
#define JS_N 16          // j-slices for rank
#define JS_W 525         // 16*525 == 8400

// ---------------- k_rank: O(N^2) stable rank, keys computed on the fly ----------------
// grid (33, 16): block (nb) ranks 256 n's against j-slice js. No atomics, no init.
__global__ __launch_bounds__(256) void k_rank(const float* __restrict__ det,
    int* __restrict__ rpart)
{
  __shared__ float tk[JS_W];
  const int tid = threadIdx.x;
  const int nb = blockIdx.x, js = blockIdx.y;
  const int n = nb*256 + tid;
  // own key (identical expression to scatter's recompute)
  float kn = 0.f;
  if (n < NB){
    float best = det[4*NB + n];
    #pragma unroll 8
    for (int c = 1; c < NCLS; ++c){
      float v = det[(4+c)*NB + n];
      if (v > best) best = v;
    }
    kn = (best >= CONFT) ? -best : __builtin_inff();
  }
  // stage this slice's j-keys (computed on the fly, deterministic)
  const int j0 = js*JS_W;
  for (int jj = tid; jj < JS_W; jj += 256){
    int j = j0 + jj;
    float best = det[4*NB + j];
    #pragma unroll 8
    for (int c = 1; c < NCLS; ++c){
      float v = det[(4+c)*NB + j];
      if (v > best) best = v;
    }
    tk[jj] = (best >= CONFT) ? -best : __builtin_inff();
  }
  __syncthreads();
  int part = 0;
  for (int jj = 0; jj < JS_W; ++jj){
    float kj = tk[jj];
    part += ((kj < kn) || (kj == kn && (j0 + jj) < n)) ? 1 : 0;  // stable: ties by index
  }
  if (n < NB) rpart[js*NB + n] = part;
}

// ---------------- k_scatter: sum rank partials, recompute key/cid, build sorted arrays ----------------
__global__ __launch_bounds__(256) void k_scatter(const float* __restrict__ det,
    const int* __restrict__ rpart, int* __restrict__ perm, int* __restrict__ scid,
    float4* __restrict__ sbox, int* __restrict__ nvp)
{
  int n = blockIdx.x*256 + threadIdx.x;
  bool valid = false;
  if (n < NB){
    float best = det[4*NB + n];
    int bc = 0;
    #pragma unroll 8
    for (int c = 1; c < NCLS; ++c){
      float v = det[(4+c)*NB + n];
      if (v > best){ best = v; bc = c; }   // strict > keeps FIRST max (matches jnp.argmax)
    }
    valid = best >= CONFT;
    int r = 0;
    #pragma unroll
    for (int js = 0; js < JS_N; ++js) r += rpart[js*NB + n];
    perm[r] = n;
    scid[r] = bc;
    float4 b;
    b.x = det[0*NB + n]; b.y = det[1*NB + n];
    b.z = det[2*NB + n]; b.w = det[3*NB + n];
    sbox[r] = b;
  }
  unsigned long long bal = __ballot(valid);
  if ((threadIdx.x & 63) == 0)
    nvp[blockIdx.x*4 + (threadIdx.x >> 6)] = (int)__popcll(bal);
}

// ---------------- k_paint: per-block supmat build + greedy scan + inline mask + paint ----------------
__global__ __launch_bounds__(256) void k_paint(const float* __restrict__ det,
    const float* __restrict__ proto, const float4* __restrict__ sbox,
    const int* __restrict__ perm, const int* __restrict__ scid,
    const int* __restrict__ nvp, float* __restrict__ out)
{
  __shared__ __align__(16) float4 lbox[T_PRE];                // 6144
  __shared__ __align__(16) unsigned long long lsup[T_PRE*TW]; // 18432
  __shared__ int   keptpos[KTOP];                             // 400
  __shared__ int4  kbox[KTOP];                                // 1600
  __shared__ int   kcid[KTOP];                                // 400
  __shared__ int   korg[KTOP];                                // 400
  __shared__ float lcoef[KTOP*NMK];                           // 12800
  __shared__ short pwcls[IW];                                 // 1280
  __shared__ short pclist[KTOP];                              // 200
  __shared__ int   s_misc[8];
  const int tid  = threadIdx.x;
  const int lane = tid & 63;
  const int wv   = tid >> 6;
  const int y    = blockIdx.x;

  // stage top-T_PRE sorted boxes
  for (int i = tid; i < T_PRE; i += 256) lbox[i] = sbox[i];
  // nvalid = sum(nvp[0..131])
  {
    int v = (tid < 132) ? nvp[tid] : 0;
    #pragma unroll
    for (int s = 32; s > 0; s >>= 1) v += __shfl_xor(v, s, 64);
    if (lane == 0) s_misc[2 + wv] = v;
  }
  __syncthreads();
  if (tid == 0) s_misc[0] = s_misc[2] + s_misc[3] + s_misc[4] + s_misc[5];
  __syncthreads();

  // build suppression bit-matrix in LDS: task t=(row i, word w), bit j = column w*64+j
  for (int t = tid; t < T_PRE*TW; t += 256){
    int i = t / TW, w = t - i*TW;
    float4 bi = lbox[i];
    float ai = (bi.z - bi.x) * (bi.w - bi.y);
    unsigned long long row = 0ull;
    #pragma unroll 8
    for (int j = 0; j < 64; ++j){
      int jg = w*64 + j;
      float4 bj = lbox[jg];
      float aj = (bj.z - bj.x) * (bj.w - bj.y);
      float ix1 = fmaxf(bi.x, bj.x), iy1 = fmaxf(bi.y, bj.y);
      float ix2 = fminf(bi.z, bj.z), iy2 = fminf(bi.w, bj.w);
      float inter = fmaxf(ix2 - ix1, 0.f) * fmaxf(iy2 - iy1, 0.f);
      bool sup = (jg > i) && (inter / (ai + aj - inter) >= IOUT);  // exact ref fp32 expr
      row |= sup ? (1ull << j) : 0ull;
    }
    lsup[t] = row;
  }
  __syncthreads();

  // greedy scan (wave 0) — verbatim verified round-5 logic
  if (tid < 64){
    const int nv = s_misc[0];
    unsigned long long keepw = 0ull;
    if (lane < TW){
      int nbits = nv - lane*64;
      if (nbits >= 64) keepw = ~0ull;
      else if (nbits > 0) keepw = (1ull << nbits) - 1ull;
    }
    int found = 0;
    const int lim = min(nv, T_PRE);
    unsigned long long r0 = (lane < TW) ? lsup[0*TW + lane] : 0ull;
    unsigned long long r1 = (lane < TW) ? lsup[1*TW + lane] : 0ull;
    for (int cand = 0; cand < lim; ++cand){
      unsigned long long r2 = (lane < TW && cand + 2 < T_PRE) ? lsup[(cand+2)*TW + lane] : 0ull;
      bool mine = (lane == (cand >> 6)) && ((keepw >> (cand & 63)) & 1ull);
      if (__ballot(mine)){                  // candidate still alive -> keep it
        if (lane == 0) keptpos[found] = cand;
        found++;
        if (found >= KTOP) break;           // 100th kept never needs to suppress
        keepw &= ~r0;                       // suppress its victims
      }
      r0 = r1; r1 = r2;
    }
    // exact fallback over sorted positions >= T_PRE (never taken on this data)
    if (found < KTOP && nv > T_PRE){
      float4 kbA = make_float4(0.f,0.f,0.f,0.f);
      float4 kbB = make_float4(0.f,0.f,0.f,0.f);
      if (lane < found)      kbA = sbox[keptpos[lane]];
      if (lane + 64 < found) kbB = sbox[keptpos[lane + 64]];
      for (int j = T_PRE; j < nv && found < KTOP; ++j){
        float4 bj = sbox[j];
        float ajj = (bj.z - bj.x) * (bj.w - bj.y);
        bool s = false;
        if (lane < found){
          float ka = (kbA.z - kbA.x) * (kbA.w - kbA.y);
          float ix1 = fmaxf(kbA.x, bj.x), iy1 = fmaxf(kbA.y, bj.y);
          float ix2 = fminf(kbA.z, bj.z), iy2 = fminf(kbA.w, bj.w);
          float inter = fmaxf(ix2 - ix1, 0.f) * fmaxf(iy2 - iy1, 0.f);
          s = inter / (ka + ajj - inter) >= IOUT;
        }
        if (lane + 64 < found){
          float ka = (kbB.z - kbB.x) * (kbB.w - kbB.y);
          float ix1 = fmaxf(kbB.x, bj.x), iy1 = fmaxf(kbB.y, bj.y);
          float ix2 = fminf(kbB.z, bj.z), iy2 = fminf(kbB.w, bj.w);
          float inter = fmaxf(ix2 - ix1, 0.f) * fmaxf(iy2 - iy1, 0.f);
          s = s || (inter / (ka + ajj - inter) >= IOUT);
        }
        if (!__ballot(s)){
          if (lane == 0) keptpos[found] = j;
          if (found < 64){ if (lane == found) kbA = bj; }
          else           { if (lane == found - 64) kbB = bj; }
          found++;
        }
      }
    }
    if (lane == 0) s_misc[1] = found;
  }
  __syncthreads();

  // gather kept-box data (global sbox: keptpos may exceed T_PRE via fallback)
  const int ns = s_misc[1];
  if (tid < ns){
    int si = keptpos[tid];
    float4 b = sbox[si];
    kbox[tid] = make_int4((int)b.x, (int)b.y, (int)b.z, (int)b.w);  // trunc==floor, coords>=0
    kcid[tid] = scid[si];
    korg[tid] = perm[si];
  }
  __syncthreads();

  // row candidate list (ascending k), wave0 ballot-prefix
  if (tid < 64){
    bool h0 = (tid < ns) && y >= kbox[tid].y && y < kbox[tid].w;
    unsigned long long m0 = __ballot(h0);
    if (h0) pclist[(int)__popcll(m0 & ((1ull << tid) - 1ull))] = (short)tid;
    int k1 = tid + 64;
    bool h1 = (k1 < ns) && y >= kbox[k1].y && y < kbox[k1].w;
    unsigned long long m1 = __ballot(h1);
    int base = (int)__popcll(m0);
    if (h1) pclist[base + (int)__popcll(m1 & ((1ull << tid) - 1ull))] = (short)k1;
    if (tid == 0) s_misc[7] = base + (int)__popcll(m1);
  }
  __syncthreads();
  const int m = s_misc[7];

  // stage coeff vectors of this row's candidates
  for (int idx = tid; idx < m*NMK; idx += 256){
    int ci = idx >> 5, mm = idx & 31;
    int so = korg[pclist[ci]];
    lcoef[idx] = det[(size_t)(84 + mm)*NB + so];
  }
  __syncthreads();

  // per-pixel: winner scan + inline mask logits (identical fmaf chain as before)
  const int fyi = (y - 2) >> 2;                      // floor((y+0.5)/4 - 0.5)
  const int ylo = max(fyi, 0), yhi = min(fyi + 1, MH_ - 1);
  for (int x = tid; x < IW; x += 256){
    int cls = -1;
    for (int ci = m - 1; ci >= 0; --ci){             // highest k containing pixel wins
      int k = pclist[ci];
      int4 b = kbox[k];
      if (x >= b.x && x < b.z){
        int fx = (x - 2) >> 2;
        int xlo = max(fx, 0), xhi = min(fx + 1, MH_ - 1);
        bool on = false;
        for (int ry = ylo; ry <= yhi; ++ry)
          for (int rx = xlo; rx <= xhi; ++rx){
            float acc = 0.f;
            #pragma unroll
            for (int mm = 0; mm < NMK; ++mm)
              acc = fmaf(lcoef[ci*NMK + mm], proto[(size_t)mm*MP + ry*MH_ + rx], acc);
            on = on || (acc > 0.f);                  // hard = sigmoid>0.5 <=> logit>0
          }
        cls = on ? kcid[k] : -1;                     // painted-zero == untouched-zero
        break;
      }
    }
    pwcls[x] = (short)cls;
  }
  __syncthreads();
  // write 640*80 floats for this row, float4-coalesced (80 % 4 == 0)
  float4* o4 = (float4*)(out + (size_t)y * (IW*NCLS));
  for (int it = 0; it < 50; ++it){
    int f4 = it*256 + tid;         // 0..12799
    int x  = f4 / 20;
    int c  = (f4 % 20) * 4;
    int wc = pwcls[x];
    float4 v;
    v.x = (wc == c    ) ? 1.f : 0.f;
    v.y = (wc == c + 1) ? 1.f : 0.f;
    v.z = (wc == c + 2) ? 1.f : 0.f;
    v.w = (wc == c + 3) ? 1.f : 0.f;
    o4[f4] = v;
  }
}

extern "C" void kernel_launch(void* const* d_in, const int* in_sizes, int n_in,
                              void* d_out, int out_size, void* d_ws, size_t ws_size,
                              hipStream_t stream)
{
  const float* det   = (const float*)d_in[0];   // (1,116,8400)
  const float* proto = (const float*)d_in[1];   // (1,32,160,160)
  float* out = (float*)d_out;                   // (1,640,640,80)
  char* w = (char*)d_ws;
  int*    rpart = (int*)   (w + 0);             // 16*8400*4 = 537600
  int*    perm  = (int*)   (w + 537600);        // 33600
  int*    scid  = (int*)   (w + 571200);        // 33600
  float4* sbox  = (float4*)(w + 604800);        // 134400, 16B aligned
  int*    nvp   = (int*)   (w + 739200);        // 528

  hipLaunchKernelGGL(k_rank,    dim3(33, JS_N), dim3(256), 0, stream, det, rpart);
  hipLaunchKernelGGL(k_scatter, dim3(33),       dim3(256), 0, stream, det, rpart, perm, scid, sbox, nvp);
  hipLaunchKernelGGL(k_paint,   dim3(IH),       dim3(256), 0, stream, det, proto, sbox, perm, scid, nvp, out);
}

// Round 12
// 282.725 us; speedup vs baseline: 2.7430x; 1.3386x over previous
//
#include <hip/hip_runtime.h>

#define NCLS 80
#define NMK  32
#define NB   8400
#define MH_  160
#define MP   25600     // 160*160
#define IH   640
#define IW   640
#define KTOP 100
#define CONFT 0.4f
#define IOUT 0.7f
#define T_PRE 384        // NMS prefix handled by bit-matrix (6 tiles of 64)
#define TW   (T_PRE/64)  // 6 u64 words per row
#define JS_N 16          // j-slices for rank
#define JS_W 525         // 16*525 == 8400

// ---------------- k_rank: O(N^2) stable rank, keys computed on the fly ----------------
__global__ __launch_bounds__(256) void k_rank(const float* __restrict__ det,
    int* __restrict__ rpart)
{
  __shared__ float tk[JS_W];
  const int tid = threadIdx.x;
  const int nb = blockIdx.x, js = blockIdx.y;
  const int n = nb*256 + tid;
  float kn = 0.f;
  if (n < NB){
    float best = det[4*NB + n];
    #pragma unroll 8
    for (int c = 1; c < NCLS; ++c){
      float v = det[(4+c)*NB + n];
      if (v > best) best = v;
    }
    kn = (best >= CONFT) ? -best : __builtin_inff();
  }
  const int j0 = js*JS_W;
  for (int jj = tid; jj < JS_W; jj += 256){
    int j = j0 + jj;
    float best = det[4*NB + j];
    #pragma unroll 8
    for (int c = 1; c < NCLS; ++c){
      float v = det[(4+c)*NB + j];
      if (v > best) best = v;
    }
    tk[jj] = (best >= CONFT) ? -best : __builtin_inff();
  }
  __syncthreads();
  int part = 0;
  for (int jj = 0; jj < JS_W; ++jj){
    float kj = tk[jj];
    part += ((kj < kn) || (kj == kn && (j0 + jj) < n)) ? 1 : 0;  // stable: ties by index
  }
  if (n < NB) rpart[js*NB + n] = part;
}

// ---------------- k_scatter: sum rank partials, recompute key/cid, build sorted arrays ----------------
__global__ __launch_bounds__(256) void k_scatter(const float* __restrict__ det,
    const int* __restrict__ rpart, int* __restrict__ perm, int* __restrict__ scid,
    float4* __restrict__ sbox, int* __restrict__ nvp)
{
  int n = blockIdx.x*256 + threadIdx.x;
  bool valid = false;
  if (n < NB){
    float best = det[4*NB + n];
    int bc = 0;
    #pragma unroll 8
    for (int c = 1; c < NCLS; ++c){
      float v = det[(4+c)*NB + n];
      if (v > best){ best = v; bc = c; }   // strict > keeps FIRST max (matches jnp.argmax)
    }
    valid = best >= CONFT;
    int r = 0;
    #pragma unroll
    for (int js = 0; js < JS_N; ++js) r += rpart[js*NB + n];
    perm[r] = n;
    scid[r] = bc;
    float4 b;
    b.x = det[0*NB + n]; b.y = det[1*NB + n];
    b.z = det[2*NB + n]; b.w = det[3*NB + n];
    sbox[r] = b;
  }
  unsigned long long bal = __ballot(valid);
  if ((threadIdx.x & 63) == 0)
    nvp[blockIdx.x*4 + (threadIdx.x >> 6)] = (int)__popcll(bal);
}

// ---------------- k_greedy2: single block, in-LDS supmat build (broadcast layout) + scan ----------------
__global__ __launch_bounds__(256) void k_greedy2(const float4* __restrict__ sbox,
    const int* __restrict__ scid, const int* __restrict__ perm, const int* __restrict__ nvp,
    int* __restrict__ selorig, int4* __restrict__ selbox, int* __restrict__ selcid,
    int* __restrict__ nsel)
{
  __shared__ __align__(16) float4 lbox[T_PRE];                 // 6144
  __shared__ __align__(16) unsigned long long lsup[T_PRE*TW];  // 18432, row-major [i][w]
  __shared__ int keptpos[KTOP];
  __shared__ int s_misc[8];
  const int tid  = threadIdx.x;
  const int lane = tid & 63;
  const int wv   = tid >> 6;
  // stage boxes + nvalid
  for (int i = tid; i < T_PRE; i += 256) lbox[i] = sbox[i];
  {
    int v = (tid < 132) ? nvp[tid] : 0;
    #pragma unroll
    for (int s = 32; s > 0; s >>= 1) v += __shfl_xor(v, s, 64);
    if (lane == 0) s_misc[2 + wv] = v;
  }
  __syncthreads();
  if (tid == 0) s_misc[0] = s_misc[2] + s_misc[3] + s_misc[4] + s_misc[5];
  __syncthreads();
  // build: t = w*T_PRE + i  (i fast) -> a wave's 64 lanes share w; lbox[w*64+j] is a broadcast.
  // (384 = 6*64, so 64-aligned t-chunks never straddle a w boundary.)
  for (int t = tid; t < T_PRE*TW; t += 256){
    int w = t / T_PRE, i = t - w*T_PRE;
    float4 bi = lbox[i];
    float ai = (bi.z - bi.x) * (bi.w - bi.y);
    unsigned long long row = 0ull;
    #pragma unroll 8
    for (int j = 0; j < 64; ++j){
      int jg = w*64 + j;
      float4 bj = lbox[jg];
      float aj = (bj.z - bj.x) * (bj.w - bj.y);
      float ix1 = fmaxf(bi.x, bj.x), iy1 = fmaxf(bi.y, bj.y);
      float ix2 = fminf(bi.z, bj.z), iy2 = fminf(bi.w, bj.w);
      float inter = fmaxf(ix2 - ix1, 0.f) * fmaxf(iy2 - iy1, 0.f);
      bool sup = (jg > i) && (inter / (ai + aj - inter) >= IOUT);  // exact ref fp32 expr
      row |= sup ? (1ull << j) : 0ull;
    }
    lsup[i*TW + w] = row;
  }
  __syncthreads();
  // greedy scan (wave 0) — verbatim verified logic
  if (tid < 64){
    const int nv = s_misc[0];
    unsigned long long keepw = 0ull;
    if (lane < TW){
      int nbits = nv - lane*64;
      if (nbits >= 64) keepw = ~0ull;
      else if (nbits > 0) keepw = (1ull << nbits) - 1ull;
    }
    int found = 0;
    const int lim = min(nv, T_PRE);
    unsigned long long r0 = (lane < TW) ? lsup[0*TW + lane] : 0ull;
    unsigned long long r1 = (lane < TW) ? lsup[1*TW + lane] : 0ull;
    for (int cand = 0; cand < lim; ++cand){
      unsigned long long r2 = (lane < TW && cand + 2 < T_PRE) ? lsup[(cand+2)*TW + lane] : 0ull;
      bool mine = (lane == (cand >> 6)) && ((keepw >> (cand & 63)) & 1ull);
      if (__ballot(mine)){                  // candidate still alive -> keep it
        if (lane == 0) keptpos[found] = cand;
        found++;
        if (found >= KTOP) break;           // 100th kept never needs to suppress
        keepw &= ~r0;                       // suppress its victims
      }
      r0 = r1; r1 = r2;
    }
    // exact fallback over sorted positions >= T_PRE (never taken on this data)
    if (found < KTOP && nv > T_PRE){
      float4 kbA = make_float4(0.f,0.f,0.f,0.f);
      float4 kbB = make_float4(0.f,0.f,0.f,0.f);
      if (lane < found)      kbA = sbox[keptpos[lane]];
      if (lane + 64 < found) kbB = sbox[keptpos[lane + 64]];
      for (int j = T_PRE; j < nv && found < KTOP; ++j){
        float4 bj = sbox[j];
        float ajj = (bj.z - bj.x) * (bj.w - bj.y);
        bool s = false;
        if (lane < found){
          float ka = (kbA.z - kbA.x) * (kbA.w - kbA.y);
          float ix1 = fmaxf(kbA.x, bj.x), iy1 = fmaxf(kbA.y, bj.y);
          float ix2 = fminf(kbA.z, bj.z), iy2 = fminf(kbA.w, bj.w);
          float inter = fmaxf(ix2 - ix1, 0.f) * fmaxf(iy2 - iy1, 0.f);
          s = inter / (ka + ajj - inter) >= IOUT;
        }
        if (lane + 64 < found){
          float ka = (kbB.z - kbB.x) * (kbB.w - kbB.y);
          float ix1 = fmaxf(kbB.x, bj.x), iy1 = fmaxf(kbB.y, bj.y);
          float ix2 = fminf(kbB.z, bj.z), iy2 = fminf(kbB.w, bj.w);
          float inter = fmaxf(ix2 - ix1, 0.f) * fmaxf(iy2 - iy1, 0.f);
          s = s || (inter / (ka + ajj - inter) >= IOUT);
        }
        if (!__ballot(s)){
          if (lane == 0) keptpos[found] = j;
          if (found < 64){ if (lane == found) kbA = bj; }
          else           { if (lane == found - 64) kbB = bj; }
          found++;
        }
      }
    }
    if (lane == 0) s_misc[1] = found;
  }
  __syncthreads();
  const int ns = s_misc[1];
  if (tid < ns){
    int si = keptpos[tid];
    float4 b = sbox[si];
    selorig[tid] = perm[si];
    selbox[tid]  = make_int4((int)b.x, (int)b.y, (int)b.z, (int)b.w); // trunc==floor, coords>=0
    selcid[tid]  = scid[si];
  }
  if (tid == 0) *nsel = ns;
}

// ---------------- k_mask: mask logits (32-dot) -> hard bits ----------------
__global__ __launch_bounds__(256) void k_mask(const float* __restrict__ det, const float* __restrict__ proto,
    const int* __restrict__ selorig, const int* __restrict__ nsel, unsigned int* __restrict__ hb)
{
  const int p    = blockIdx.x*256 + threadIdx.x;          // 0..25599
  const int lane = threadIdx.x & 63;
  const int wword = (blockIdx.x*256 + (threadIdx.x & ~63)) >> 5;  // 2 u32 words per wave
  float pr[NMK];
  #pragma unroll
  for (int m = 0; m < NMK; ++m) pr[m] = proto[m*MP + p];
  const int ns = *nsel;
  const int k0 = blockIdx.y * 10;
  for (int kk = 0; kk < 10; ++kk){
    int k = k0 + kk;
    if (k >= ns) break;                                   // uniform
    int so = selorig[k];
    const float* cf = det + 84*NB + so;                   // uniform -> scalar loads
    float acc = 0.f;
    #pragma unroll
    for (int m = 0; m < NMK; ++m) acc = fmaf(cf[(size_t)m*NB], pr[m], acc);
    unsigned long long bal = __ballot(acc > 0.f);         // hard = sigmoid>0.5 <=> logit>0
    if (lane == 0)  hb[k*800 + wword]     = (unsigned int)bal;
    if (lane == 32) hb[k*800 + wword + 1] = (unsigned int)(bal >> 32);
  }
}

// ---------------- k_paint: winner-per-pixel + coalesced one-hot row writes ----------------
__global__ __launch_bounds__(256) void k_paint(const int4* __restrict__ selbox, const int* __restrict__ selcid,
    const int* __restrict__ nsel, const unsigned int* __restrict__ hb, float* __restrict__ out)
{
  __shared__ int4  sbx[KTOP];
  __shared__ int   scd[KTOP];
  __shared__ short wcls[IW];
  __shared__ short clist[KTOP];
  __shared__ int   ccount;
  const int y = blockIdx.x;
  const int tid = threadIdx.x;
  const int ns = *nsel;
  if (tid < ns){ sbx[tid] = selbox[tid]; scd[tid] = selcid[tid]; }
  if (tid == 0) ccount = 0;
  __syncthreads();
  if (tid == 0){  // boxes intersecting this row, ascending k
    int m = 0;
    for (int k = 0; k < ns; ++k)
      if (y >= sbx[k].y && y < sbx[k].w) clist[m++] = (short)k;
    ccount = m;
  }
  __syncthreads();
  const int m = ccount;
  const int fyi = (y - 2) >> 2;                      // floor((y+0.5)/4 - 0.5)
  const int ylo = max(fyi, 0), yhi = min(fyi + 1, MH_ - 1);
  for (int x = tid; x < IW; x += 256){
    int cls = -1;
    for (int ci = m - 1; ci >= 0; --ci){             // highest k containing pixel wins
      int k = clist[ci];
      int4 b = sbx[k];
      if (x >= b.x && x < b.z){
        int fx = (x - 2) >> 2;
        int xlo = max(fx, 0), xhi = min(fx + 1, MH_ - 1);
        bool on = false;
        for (int ry = ylo; ry <= yhi; ++ry)
          for (int rx = xlo; rx <= xhi; ++rx){
            int pp = ry*MH_ + rx;
            on = on || ((hb[k*800 + (pp >> 5)] >> (pp & 31)) & 1u);
          }
        cls = on ? scd[k] : -1;                      // painted-zero == untouched-zero
        break;
      }
    }
    wcls[x] = (short)cls;
  }
  __syncthreads();
  // write 640*80 floats for this row, float4-coalesced (80 % 4 == 0)
  float4* o4 = (float4*)(out + (size_t)y * (IW*NCLS));
  for (int it = 0; it < 50; ++it){
    int f4 = it*256 + tid;         // 0..12799
    int x  = f4 / 20;
    int c  = (f4 % 20) * 4;
    int wc = wcls[x];
    float4 v;
    v.x = (wc == c    ) ? 1.f : 0.f;
    v.y = (wc == c + 1) ? 1.f : 0.f;
    v.z = (wc == c + 2) ? 1.f : 0.f;
    v.w = (wc == c + 3) ? 1.f : 0.f;
    o4[f4] = v;
  }
}

extern "C" void kernel_launch(void* const* d_in, const int* in_sizes, int n_in,
                              void* d_out, int out_size, void* d_ws, size_t ws_size,
                              hipStream_t stream)
{
  const float* det   = (const float*)d_in[0];   // (1,116,8400)
  const float* proto = (const float*)d_in[1];   // (1,32,160,160)
  float* out = (float*)d_out;                   // (1,640,640,80)
  char* w = (char*)d_ws;
  int*    rpart   = (int*)   (w + 0);           // 537600
  int*    perm    = (int*)   (w + 537600);      // 33600
  int*    scid    = (int*)   (w + 571200);      // 33600
  float4* sbox    = (float4*)(w + 604800);      // 134400, 16B aligned
  int*    nvp     = (int*)   (w + 739200);      // 528
  int*    selorig = (int*)   (w + 739728);      // 400
  int4*   selbox  = (int4*)  (w + 740144);      // 1600, 16B aligned
  int*    selcid  = (int*)   (w + 741744);      // 400
  int*    nsel    = (int*)   (w + 742144);      // 4
  unsigned int* hb = (unsigned int*)(w + 742160);  // 320000

  hipLaunchKernelGGL(k_rank,    dim3(33, JS_N), dim3(256), 0, stream, det, rpart);
  hipLaunchKernelGGL(k_scatter, dim3(33),       dim3(256), 0, stream, det, rpart, perm, scid, sbox, nvp);
  hipLaunchKernelGGL(k_greedy2, dim3(1),        dim3(256), 0, stream, sbox, scid, perm, nvp,
                     selorig, selbox, selcid, nsel);
  hipLaunchKernelGGL(k_mask,    dim3(100, 10),  dim3(256), 0, stream, det, proto, selorig, nsel, hb);
  hipLaunchKernelGGL(k_paint,   dim3(IH),       dim3(256), 0, stream, selbox, selcid, nsel, hb, out);
}

// Round 14
// 239.362 us; speedup vs baseline: 3.2399x; 1.1812x over previous
//
#include <hip/hip_runtime.h>

#define NCLS 80
#define NMK  32
#define NB   8400
#define MH_  160
#define MP   25600     // 160*160
#define IH   640
#define IW   640
#define KTOP 100
#define CONFT 0.4f
#define IOUT 0.7f
#define T_PRE 384        // NMS prefix handled by bit-matrix (6 tiles of 64)
#define TW   (T_PRE/64)  // 6 u64 words per row
#define JS_N 16          // j-slices for rank
#define JS_W 525         // 16*525 == 8400

// ---------------- k_rank: O(N^2) stable rank, keys computed on the fly ----------------
__global__ __launch_bounds__(256) void k_rank(const float* __restrict__ det,
    int* __restrict__ rpart)
{
  __shared__ float tk[JS_W];
  const int tid = threadIdx.x;
  const int nb = blockIdx.x, js = blockIdx.y;
  const int n = nb*256 + tid;
  float kn = 0.f;
  if (n < NB){
    float best = det[4*NB + n];
    #pragma unroll 8
    for (int c = 1; c < NCLS; ++c){
      float v = det[(4+c)*NB + n];
      if (v > best) best = v;
    }
    kn = (best >= CONFT) ? -best : __builtin_inff();
  }
  const int j0 = js*JS_W;
  for (int jj = tid; jj < JS_W; jj += 256){
    int j = j0 + jj;
    float best = det[4*NB + j];
    #pragma unroll 8
    for (int c = 1; c < NCLS; ++c){
      float v = det[(4+c)*NB + j];
      if (v > best) best = v;
    }
    tk[jj] = (best >= CONFT) ? -best : __builtin_inff();
  }
  __syncthreads();
  int part = 0;
  for (int jj = 0; jj < JS_W; ++jj){
    float kj = tk[jj];
    part += ((kj < kn) || (kj == kn && (j0 + jj) < n)) ? 1 : 0;  // stable: ties by index
  }
  if (n < NB) rpart[js*NB + n] = part;
}

// ---------------- k_scatter: sum rank partials, recompute key/cid, build sorted arrays ----------------
__global__ __launch_bounds__(256) void k_scatter(const float* __restrict__ det,
    const int* __restrict__ rpart, int* __restrict__ perm, int* __restrict__ scid,
    float4* __restrict__ sbox, int* __restrict__ nvp)
{
  int n = blockIdx.x*256 + threadIdx.x;
  bool valid = false;
  if (n < NB){
    float best = det[4*NB + n];
    int bc = 0;
    #pragma unroll 8
    for (int c = 1; c < NCLS; ++c){
      float v = det[(4+c)*NB + n];
      if (v > best){ best = v; bc = c; }   // strict > keeps FIRST max (matches jnp.argmax)
    }
    valid = best >= CONFT;
    int r = 0;
    #pragma unroll
    for (int js = 0; js < JS_N; ++js) r += rpart[js*NB + n];
    perm[r] = n;
    scid[r] = bc;
    float4 b;
    b.x = det[0*NB + n]; b.y = det[1*NB + n];
    b.z = det[2*NB + n]; b.w = det[3*NB + n];
    sbox[r] = b;
  }
  unsigned long long bal = __ballot(valid);
  if ((threadIdx.x & 63) == 0)
    nvp[blockIdx.x*4 + (threadIdx.x >> 6)] = (int)__popcll(bal);
}

// ---------------- k_supmat: pairwise suppression bits, one wave per 64x64 tile (parallel!) ----------------
__global__ __launch_bounds__(64) void k_supmat(const float4* __restrict__ sbox,
    unsigned long long* __restrict__ supmat)
{
  const int lane = threadIdx.x;
  const int ti = blockIdx.x;           // 0..TW-1
  const int tj = blockIdx.y;           // 0..TW-1
  float4 bj = sbox[tj*64 + lane];
  float aj = (bj.z - bj.x) * (bj.w - bj.y);
  float4 bi_all = sbox[ti*64 + lane];
  float ai_all  = (bi_all.z - bi_all.x) * (bi_all.w - bi_all.y);
  const int jg = tj*64 + lane;
  unsigned long long myrow = 0ull;
  #pragma unroll 4
  for (int ii = 0; ii < 64; ++ii){
    float bix = __shfl(bi_all.x, ii, 64);
    float biy = __shfl(bi_all.y, ii, 64);
    float biz = __shfl(bi_all.z, ii, 64);
    float biw = __shfl(bi_all.w, ii, 64);
    float ai  = __shfl(ai_all,  ii, 64);
    float ix1 = fmaxf(bix, bj.x), iy1 = fmaxf(biy, bj.y);
    float ix2 = fminf(biz, bj.z), iy2 = fminf(biw, bj.w);
    float inter = fmaxf(ix2 - ix1, 0.f) * fmaxf(iy2 - iy1, 0.f);
    bool sup = (jg > ti*64 + ii) && (inter / (ai + aj - inter) >= IOUT);  // exact ref fp32 expr
    unsigned long long bal = __ballot(sup);
    if (lane == ii) myrow = bal;
  }
  supmat[(size_t)(ti*64 + lane)*TW + tj] = myrow;
}

// ---------------- k_greedy: 18KB LDS copy + single-wave sequential scan (verbatim R5) ----------------
__global__ __launch_bounds__(1024) void k_greedy(const float4* __restrict__ sbox,
    const int* __restrict__ scid, const int* __restrict__ perm,
    const unsigned long long* __restrict__ supmat, const int* __restrict__ nvp,
    int* __restrict__ selorig, int4* __restrict__ selbox, int* __restrict__ selcid,
    int* __restrict__ nsel)
{
  __shared__ __align__(16) unsigned long long lsup[T_PRE*TW];  // 18 KB
  __shared__ int keptpos[KTOP];
  __shared__ int partial[192];
  __shared__ int s_nv;
  __shared__ int s_found;
  const int tid = threadIdx.x;
  // cooperative copy: 384*6 u64 = 1152 float4  (+ load nvalid partials)
  {
    const float4* g4 = (const float4*)supmat;
    float4* l4 = (float4*)lsup;
    for (int idx = tid; idx < (T_PRE*TW)/2; idx += 1024) l4[idx] = g4[idx];
    partial[tid & 191] = 0;                  // covers 0..191 (1024 threads wrap)
  }
  __syncthreads();
  if (tid < 132) partial[tid] = nvp[tid];
  __syncthreads();
  if (tid < 64){
    int s = partial[tid] + partial[tid + 64] + ((tid + 128 < 192) ? partial[tid + 128] : 0);
    #pragma unroll
    for (int sh = 32; sh > 0; sh >>= 1) s += __shfl_xor(s, sh, 64);
    if (tid == 0) s_nv = s;
  }
  __syncthreads();

  if (tid < 64){
    const int lane = tid;
    const int nv = s_nv;
    // keep-word init: sorted position valid <=> pos < nvalid (finite keys sort first)
    unsigned long long keepw = 0ull;
    if (lane < TW){
      int nbits = nv - lane*64;
      if (nbits >= 64) keepw = ~0ull;
      else if (nbits > 0) keepw = (1ull << nbits) - 1ull;
    }
    int found = 0;
    const int lim = min(nv, T_PRE);
    // sequential candidate scan; static rows -> unconditional depth-2 prefetch
    unsigned long long r0 = (lane < TW) ? lsup[0*TW + lane] : 0ull;
    unsigned long long r1 = (lane < TW) ? lsup[1*TW + lane] : 0ull;
    for (int cand = 0; cand < lim; ++cand){
      unsigned long long r2 = (lane < TW && cand + 2 < T_PRE) ? lsup[(cand+2)*TW + lane] : 0ull;
      bool mine = (lane == (cand >> 6)) && ((keepw >> (cand & 63)) & 1ull);
      if (__ballot(mine)){                  // candidate still alive -> keep it
        if (lane == 0) keptpos[found] = cand;
        found++;
        if (found >= KTOP) break;           // 100th kept never needs to suppress
        keepw &= ~r0;                       // suppress its victims
      }
      r0 = r1; r1 = r2;
    }
    // exact fallback over sorted positions >= T_PRE (never taken on this data)
    if (found < KTOP && nv > T_PRE){
      float4 kbA = make_float4(0.f,0.f,0.f,0.f);
      float4 kbB = make_float4(0.f,0.f,0.f,0.f);
      if (lane < found)      kbA = sbox[keptpos[lane]];
      if (lane + 64 < found) kbB = sbox[keptpos[lane + 64]];
      for (int j = T_PRE; j < nv && found < KTOP; ++j){
        float4 bj = sbox[j];
        float ajj = (bj.z - bj.x) * (bj.w - bj.y);
        bool s = false;
        if (lane < found){
          float ka = (kbA.z - kbA.x) * (kbA.w - kbA.y);
          float ix1 = fmaxf(kbA.x, bj.x), iy1 = fmaxf(kbA.y, bj.y);
          float ix2 = fminf(kbA.z, bj.z), iy2 = fminf(kbA.w, bj.w);
          float inter = fmaxf(ix2 - ix1, 0.f) * fmaxf(iy2 - iy1, 0.f);
          s = inter / (ka + ajj - inter) >= IOUT;
        }
        if (lane + 64 < found){
          float ka = (kbB.z - kbB.x) * (kbB.w - kbB.y);
          float ix1 = fmaxf(kbB.x, bj.x), iy1 = fmaxf(kbB.y, bj.y);
          float ix2 = fminf(kbB.z, bj.z), iy2 = fminf(kbB.w, bj.w);
          float inter = fmaxf(ix2 - ix1, 0.f) * fmaxf(iy2 - iy1, 0.f);
          s = s || (inter / (ka + ajj - inter) >= IOUT);
        }
        if (!__ballot(s)){
          if (lane == 0) keptpos[found] = j;
          if (found < 64){ if (lane == found) kbA = bj; }
          else           { if (lane == found - 64) kbB = bj; }
          found++;
        }
      }
    }
    if (lane == 0) s_found = found;
  }
  __syncthreads();
  const int ns = s_found;
  if (tid < ns){
    int si = keptpos[tid];
    float4 b = sbox[si];
    selorig[tid] = perm[si];
    selbox[tid]  = make_int4((int)b.x, (int)b.y, (int)b.z, (int)b.w); // trunc==floor, coords>=0
    selcid[tid]  = scid[si];
  }
  if (tid == 0) *nsel = ns;
}

// ---------------- k_mask: mask logits (32-dot) -> hard bits ----------------
__global__ __launch_bounds__(256) void k_mask(const float* __restrict__ det, const float* __restrict__ proto,
    const int* __restrict__ selorig, const int* __restrict__ nsel, unsigned int* __restrict__ hb)
{
  const int p    = blockIdx.x*256 + threadIdx.x;          // 0..25599
  const int lane = threadIdx.x & 63;
  const int wword = (blockIdx.x*256 + (threadIdx.x & ~63)) >> 5;  // 2 u32 words per wave
  float pr[NMK];
  #pragma unroll
  for (int m = 0; m < NMK; ++m) pr[m] = proto[m*MP + p];
  const int ns = *nsel;
  const int k0 = blockIdx.y * 10;
  for (int kk = 0; kk < 10; ++kk){
    int k = k0 + kk;
    if (k >= ns) break;                                   // uniform
    int so = selorig[k];
    const float* cf = det + 84*NB + so;                   // uniform -> scalar loads
    float acc = 0.f;
    #pragma unroll
    for (int m = 0; m < NMK; ++m) acc = fmaf(cf[(size_t)m*NB], pr[m], acc);
    unsigned long long bal = __ballot(acc > 0.f);         // hard = sigmoid>0.5 <=> logit>0
    if (lane == 0)  hb[k*800 + wword]     = (unsigned int)bal;
    if (lane == 32) hb[k*800 + wword + 1] = (unsigned int)(bal >> 32);
  }
}

// ---------------- k_paint: winner-per-pixel + coalesced one-hot row writes ----------------
__global__ __launch_bounds__(256) void k_paint(const int4* __restrict__ selbox, const int* __restrict__ selcid,
    const int* __restrict__ nsel, const unsigned int* __restrict__ hb, float* __restrict__ out)
{
  __shared__ int4  sbx[KTOP];
  __shared__ int   scd[KTOP];
  __shared__ short wcls[IW];
  __shared__ short clist[KTOP];
  __shared__ int   ccount;
  const int y = blockIdx.x;
  const int tid = threadIdx.x;
  const int ns = *nsel;
  if (tid < ns){ sbx[tid] = selbox[tid]; scd[tid] = selcid[tid]; }
  if (tid == 0) ccount = 0;
  __syncthreads();
  if (tid == 0){  // boxes intersecting this row, ascending k
    int m = 0;
    for (int k = 0; k < ns; ++k)
      if (y >= sbx[k].y && y < sbx[k].w) clist[m++] = (short)k;
    ccount = m;
  }
  __syncthreads();
  const int m = ccount;
  const int fyi = (y - 2) >> 2;                      // floor((y+0.5)/4 - 0.5)
  const int ylo = max(fyi, 0), yhi = min(fyi + 1, MH_ - 1);
  for (int x = tid; x < IW; x += 256){
    int cls = -1;
    for (int ci = m - 1; ci >= 0; --ci){             // highest k containing pixel wins
      int k = clist[ci];
      int4 b = sbx[k];
      if (x >= b.x && x < b.z){
        int fx = (x - 2) >> 2;
        int xlo = max(fx, 0), xhi = min(fx + 1, MH_ - 1);
        bool on = false;
        for (int ry = ylo; ry <= yhi; ++ry)
          for (int rx = xlo; rx <= xhi; ++rx){
            int pp = ry*MH_ + rx;
            on = on || ((hb[k*800 + (pp >> 5)] >> (pp & 31)) & 1u);
          }
        cls = on ? scd[k] : -1;                      // painted-zero == untouched-zero
        break;
      }
    }
    wcls[x] = (short)cls;
  }
  __syncthreads();
  // write 640*80 floats for this row, float4-coalesced (80 % 4 == 0)
  float4* o4 = (float4*)(out + (size_t)y * (IW*NCLS));
  for (int it = 0; it < 50; ++it){
    int f4 = it*256 + tid;         // 0..12799
    int x  = f4 / 20;
    int c  = (f4 % 20) * 4;
    int wc = wcls[x];
    float4 v;
    v.x = (wc == c    ) ? 1.f : 0.f;
    v.y = (wc == c + 1) ? 1.f : 0.f;
    v.z = (wc == c + 2) ? 1.f : 0.f;
    v.w = (wc == c + 3) ? 1.f : 0.f;
    o4[f4] = v;
  }
}

extern "C" void kernel_launch(void* const* d_in, const int* in_sizes, int n_in,
                              void* d_out, int out_size, void* d_ws, size_t ws_size,
                              hipStream_t stream)
{
  const float* det   = (const float*)d_in[0];   // (1,116,8400)
  const float* proto = (const float*)d_in[1];   // (1,32,160,160)
  float* out = (float*)d_out;                   // (1,640,640,80)
  char* w = (char*)d_ws;
  int*    rpart   = (int*)   (w + 0);           // 537600
  int*    perm    = (int*)   (w + 537600);      // 33600
  int*    scid    = (int*)   (w + 571200);      // 33600
  float4* sbox    = (float4*)(w + 604800);      // 134400, 16B aligned
  int*    nvp     = (int*)   (w + 739200);      // 528
  int*    selorig = (int*)   (w + 739728);      // 400
  int4*   selbox  = (int4*)  (w + 740144);      // 1600, 16B aligned
  int*    selcid  = (int*)   (w + 741744);      // 400
  int*    nsel    = (int*)   (w + 742144);      // 4
  unsigned int* hb = (unsigned int*)(w + 742160);                 // 320000
  unsigned long long* supmat = (unsigned long long*)(w + 1062160); // 18432

  hipLaunchKernelGGL(k_rank,    dim3(33, JS_N), dim3(256),  0, stream, det, rpart);
  hipLaunchKernelGGL(k_scatter, dim3(33),       dim3(256),  0, stream, det, rpart, perm, scid, sbox, nvp);
  hipLaunchKernelGGL(k_supmat,  dim3(TW, TW),   dim3(64),   0, stream, sbox, supmat);
  hipLaunchKernelGGL(k_greedy,  dim3(1),        dim3(1024), 0, stream, sbox, scid, perm, supmat, nvp,
                     selorig, selbox, selcid, nsel);
  hipLaunchKernelGGL(k_mask,    dim3(100, 10),  dim3(256),  0, stream, det, proto, selorig, nsel, hb);
  hipLaunchKernelGGL(k_paint,   dim3(IH),       dim3(256),  0, stream, selbox, selcid, nsel, hb, out);
}